// Round 15
// baseline (3451.421 us; speedup 1.0000x reference)
//
#include <hip/hip_runtime.h>

// ---------------------------------------------------------------------------
// Bidirectional GRU encoder (Keras v2, reset_after=True, mask_zero)
// Round 15: de-scaffolded scan step. Rounds 11-14 proved (5 neutral A/Bs)
// the floor isn't traffic/drains/occupancy/stores: it's the 5-barrier
// + 2-LDS-roundtrip + single-wave-poll scaffold. Now:
//   - XP+tok prefetched per-lane into REGISTERS (no xb LDS, no B1)
//   - h stored directly from owner lanes as coherent u16 (no bounce, no B2)
//   - per-WAVE flags (32/group, 64B-padded): each kh=0 wave drains only its
//     own stores then adds; EVERY wave polls all 32 flags itself (no B3/B4)
//   - ONE intra-WG barrier/step (K-half partial handoff, red[s&1] dbuf)
//   - acquire fence 1/16 steps by wave 0, bracketed by 2 barriers (amortized)
// ---------------------------------------------------------------------------

#define T_SEQ 256
#define BATCH 128
#define EMB_D 512
#define UNITS 1024
#define NROWS (BATCH * T_SEQ) /* 32768 */
#define N3U 3072
#define N6U 6144
// XPn element strides: [t]=786432, [dir]=393216, [ut]=6144, [b]=48, [g]=16
#define XT_STRIDE 786432
#define HSTR (BATCH * 2048) /* elements per h buffer (512 KB) */
#define HROT 16

#define SBAR()      __builtin_amdgcn_s_barrier()
#define SCHED0()    __builtin_amdgcn_sched_barrier(0)
#define WAIT_LGKM() asm volatile("s_waitcnt lgkmcnt(0)" ::: "memory")
#define WAIT_VM()   asm volatile("s_waitcnt vmcnt(0)" ::: "memory")

typedef __attribute__((ext_vector_type(8))) __bf16 bfv8;
typedef __attribute__((ext_vector_type(4))) float f32x4;

__device__ inline unsigned short f2bf(float f) {
  union { float f; unsigned int u; } x; x.f = f;
  unsigned int u = x.u;
  unsigned int r = (u + 0x7fffu + ((u >> 16) & 1u)) >> 16; // RNE
  return (unsigned short)r;
}
__device__ inline float bf2f(unsigned short h) {
  union { unsigned int u; float f; } x; x.u = ((unsigned int)h) << 16;
  return x.f;
}
__device__ inline f32x4 mfma16(bfv8 a, bfv8 b, f32x4 c) {
  return __builtin_amdgcn_mfma_f32_16x16x32_bf16(a, b, c, 0, 0, 0);
}
__device__ inline void gl_lds16(const unsigned short* g, unsigned short* l) {
  __builtin_amdgcn_global_load_lds(
      (const __attribute__((address_space(1))) void*)g,
      (__attribute__((address_space(3))) void*)l, 16, 0, 0);
}

// dst[N][K] (bf16) = src[K][N] (f32), 32x32 LDS-tiled transpose
__global__ __launch_bounds__(256) void k_transpose(const float* __restrict__ src,
                                                   unsigned short* __restrict__ dst,
                                                   int K, int N) {
  __shared__ float tile[32][33];
  int k0 = blockIdx.x * 32, n0 = blockIdx.y * 32;
  int tx = threadIdx.x & 31, ty = threadIdx.x >> 5;
#pragma unroll
  for (int i = 0; i < 4; ++i)
    tile[ty + i * 8][tx] = src[(size_t)(k0 + ty + i * 8) * N + n0 + tx];
  __syncthreads();
#pragma unroll
  for (int i = 0; i < 4; ++i)
    dst[(size_t)(n0 + ty + i * 8) * K + k0 + tx] = f2bf(tile[tx][ty + i * 8]);
}

// Xbf[32768][512] bf16 = emb[tokens[row]]
__global__ __launch_bounds__(256) void k_gather(const int* __restrict__ tokens,
                                                const float* __restrict__ emb,
                                                unsigned short* __restrict__ Xbf) {
  int idx = blockIdx.x * 256 + threadIdx.x; // one float4 per thread
  int row = idx >> 7;
  int c4 = (idx & 127) * 4;
  int tok = tokens[row];
  float4 v = *(const float4*)(emb + (size_t)tok * EMB_D + c4);
  ushort4 p;
  p.x = f2bf(v.x); p.y = f2bf(v.y); p.z = f2bf(v.z); p.w = f2bf(v.w);
  *(ushort4*)(Xbf + (size_t)row * EMB_D + c4) = p;
}

// biasX[6144] = [b_f[0] | b_b[0]],  biasH[6144] = [b_f[1] | b_b[1]]
__global__ __launch_bounds__(256) void k_bias(const float* __restrict__ bf_,
                                              const float* __restrict__ bb_,
                                              float* __restrict__ biasX,
                                              float* __restrict__ biasH) {
  int i = blockIdx.x * 256 + threadIdx.x;
  if (i >= N6U) return;
  if (i < N3U) { biasX[i] = bf_[i];        biasH[i] = bf_[N3U + i]; }
  else         { biasX[i] = bb_[i - N3U];  biasH[i] = bb_[i]; }
}

// tokT[t][b] = tokens[b][t]
__global__ __launch_bounds__(256) void k_tokt(const int* __restrict__ tokens,
                                              int* __restrict__ tokT) {
  int i = blockIdx.x * 256 + threadIdx.x; // 32768
  int b = i >> 8, t = i & 255;
  tokT[t * BATCH + b] = tokens[i];
}

// C = A[M][K](bf16) @ BT[N][K](bf16)^T + bias[N]
// mode 0: scatter bf16 into XPn[t][dir][ut][b][g][16]; mode 1: f32 row-major.
__global__ __launch_bounds__(256) void k_gemm(const unsigned short* __restrict__ A,
                                              const unsigned short* __restrict__ BT,
                                              const float* __restrict__ bias,
                                              void* __restrict__ C,
                                              int M, int N, int K, int mode) {
  __shared__ unsigned short As[128 * 32];
  __shared__ unsigned short Bs[128 * 32];
  const int mt = blockIdx.x, nt = blockIdx.y;
  const int tid = threadIdx.x;
  const int wid = tid >> 6, lane = tid & 63;
  const int wm = (wid >> 1) * 64, wn = (wid & 1) * 64;
  const int l15 = lane & 15, lk = (lane >> 4) * 8;

  f32x4 acc[4][4];
#pragma unroll
  for (int i = 0; i < 4; ++i)
#pragma unroll
    for (int j = 0; j < 4; ++j) acc[i][j] = (f32x4){0.f, 0.f, 0.f, 0.f};

  const int r = tid >> 2;          // staging row 0..63
  const int cc = (tid & 3) * 8;    // staging col (elements)
  const unsigned short* ga0 = A + (size_t)(mt * 128 + r) * K + cc;
  const unsigned short* ga1 = ga0 + (size_t)64 * K;
  const unsigned short* gb0 = BT + (size_t)(nt * 128 + r) * K + cc;
  const unsigned short* gb1 = gb0 + (size_t)64 * K;
  unsigned short* lA0 = As + r * 32 + cc;        // byte off = tid*16, wave-linear
  unsigned short* lA1 = As + (64 + r) * 32 + cc;
  unsigned short* lB0 = Bs + r * 32 + cc;
  unsigned short* lB1 = Bs + (64 + r) * 32 + cc;

  for (int k0 = 0; k0 < K; k0 += 32) {
    __syncthreads(); // previous iter's LDS reads complete
    gl_lds16(ga0 + k0, lA0);
    gl_lds16(ga1 + k0, lA1);
    gl_lds16(gb0 + k0, lB0);
    gl_lds16(gb1 + k0, lB1);
    __syncthreads(); // loads landed
    bfv8 af[4], bfr[4];
#pragma unroll
    for (int i = 0; i < 4; ++i) {
      af[i]  = *(const bfv8*)(As + (wm + i * 16 + l15) * 32 + lk);
      bfr[i] = *(const bfv8*)(Bs + (wn + i * 16 + l15) * 32 + lk);
    }
#pragma unroll
    for (int i = 0; i < 4; ++i)
#pragma unroll
      for (int j = 0; j < 4; ++j) acc[i][j] = mfma16(af[i], bfr[j], acc[i][j]);
  }

#pragma unroll
  for (int j = 0; j < 4; ++j) {
    const int col = nt * 128 + wn + j * 16 + l15;
    const float bv = bias[col];
    const int dirc = (col >= N3U) ? 1 : 0;
    const int cm = col - dirc * N3U;
    const int g = cm >> 10;
    const int uu = cm & 1023;
    const size_t cbase = (size_t)dirc * 393216 + (size_t)(uu >> 4) * 6144 +
                         (size_t)g * 16 + (uu & 15);
#pragma unroll
    for (int i = 0; i < 4; ++i) {
      const int row0 = mt * 128 + wm + i * 16 + (lane >> 4) * 4;
#pragma unroll
      for (int q = 0; q < 4; ++q) {
        const float v = acc[i][j][q] + bv;
        const int row = row0 + q;
        if (mode == 1) {
          ((float*)C)[(size_t)row * N + col] = v;
        } else {
          const int b = row >> 8, tt = row & 255;
          ((unsigned short*)C)[(size_t)tt * XT_STRIDE + cbase + (size_t)b * 48] = f2bf(v);
        }
      }
    }
  }
}

// ---------------------------------------------------------------------------
// Persistent fused GRU scan. Grid = 256 WGs x 512 threads (8 waves = 2/SIMD):
//   grp = bid&3 -> (dir,mg); ut = bid>>2 (group g on XCDs g and g+4).
// Wave w: row-block wlo=w&3, K-half kh=w>>2. ALL gate weights in 96KB LDS.
// Per step: [poll 32 flags, every wave] -> h loads -> MFMA -> kh=1 writes
// partials red[s&1] -> s_barrier -> kh=0 reduce+epilogue -> coherent u16 h
// stores + out stores -> own vmcnt(0) -> lane0 flag add. Fence 1/16 steps.
// ---------------------------------------------------------------------------
__global__ __launch_bounds__(512) void k_scan(const unsigned short* __restrict__ XPn,
                                              const unsigned short* __restrict__ WhT,
                                              const float* __restrict__ biasH,
                                              const int* __restrict__ tokT,
                                              unsigned short* __restrict__ hbR,
                                              float* __restrict__ out,
                                              unsigned int* __restrict__ bar) {
  __shared__ unsigned short Wl[3 * 128 * 16 * 8]; // 96 KB  [g][kb][u][8]
  __shared__ float red[2][4][64][13];             // 26.6 KB partials, dbuf

  const int bid = blockIdx.x;
  const int grp = bid & 3;   // one group per {XCD g, XCD g+4} pair
  const int dir = grp >> 1;
  const int mg  = grp & 1;
  const int ut  = bid >> 2;  // 0..63
  const int u0 = ut * 16, m0 = mg * 64;
  const int tid = threadIdx.x;

  // stage all 3 gates' Wh slice -> LDS (once)
  for (int c = tid; c < 6144; c += 512) {
    const int g  = c >> 11;         // gate
    const int kb = (c >> 4) & 127;  // k-block of 8
    const int uu = c & 15;
    *(uint4*)(Wl + (((g << 7) | kb) * 16 + uu) * 8) =
        *(const uint4*)(WhT + (((size_t)(dir * N3U + (g << 10) + u0 + uu)) << 10) + (kb << 3));
  }

  const int lane = tid & 63, wid = tid >> 6;   // wid 0..7
  const int wlo = wid & 3, kh = wid >> 2;      // row-block, K-half
  const int l15 = lane & 15, hi = lane >> 4;
  const size_t aoff = ((size_t)(m0 + wlo * 16 + l15) << 11) + (dir << 10) + (kh << 9) + (hi << 3);
  const int u = u0 + l15;
  const float bz  = biasH[dir * N3U + u];
  const float brg = biasH[dir * N3U + 1024 + u];
  const float bhg = biasH[dir * N3U + 2048 + u];
  const int rb = wlo * 16 + (hi << 2); // local row of this lane's 4 outputs
  const int ob = m0 + rb;
  const size_t woff = (dir << 10) + u;

  // per-wave flag (kh=0 waves add): 32 sub-flags per group, 64B-padded
  unsigned int* myflag = &bar[((grp << 5) | ((ut & 7) << 2) | wid) << 4];

  // contiguous per-step XP tile base for this WG
  const unsigned short* xpb = XPn + (size_t)dir * 393216 + (size_t)ut * 6144 + (size_t)m0 * 48;

  // prologue prefetch: step 0 (kh=0 lanes own 12 XP u16s + 4 tokens)
  unsigned short px[12]; int4 ptok = {0, 0, 0, 0};
  if (kh == 0) {
    const int t0 = dir ? (T_SEQ - 1) : 0;
    const unsigned short* xs = xpb + (size_t)t0 * XT_STRIDE;
#pragma unroll
    for (int q = 0; q < 4; ++q)
#pragma unroll
      for (int g = 0; g < 3; ++g)
        px[q * 3 + g] = xs[(rb + q) * 48 + g * 16 + l15];
    ptok = *(const int4*)(tokT + t0 * BATCH + ob);
  }

  float hreg[4] = {0.f, 0.f, 0.f, 0.f};
  __syncthreads(); // Wl staged

  for (int s = 0; s < T_SEQ; ++s) {
    const int t = dir ? (T_SEQ - 1 - s) : s;
    const unsigned short* hrd = hbR + (size_t)((s + HROT - 1) & (HROT - 1)) * HSTR; // h_{s-1}
    unsigned short* hwr       = hbR + (size_t)(s & (HROT - 1)) * HSTR;              // h_s

    if (s > 0) {
      // every wave self-releases: lanes 0-31 poll the group's 32 flags
      if (lane < 32) {
        const unsigned tgt = 8u * (unsigned)s; // 8 adds per flag per step
        unsigned int* p = &bar[((grp << 5) | lane) << 4];
        while (__hip_atomic_load(p, __ATOMIC_RELAXED, __HIP_MEMORY_SCOPE_AGENT) < tgt)
          __builtin_amdgcn_s_sleep(2);
      }
      SCHED0();
      if ((s & (HROT - 1)) == 0) {
        // rotation boundary: one fence per WG (wave 0), bracketed by barriers
        SBAR(); SCHED0();
        if (wid == 0) __builtin_amdgcn_fence(__ATOMIC_ACQUIRE, "agent");
        SCHED0(); SBAR(); SCHED0();
      }
    }

    // h loads + MFMA over this wave's K-half
    const unsigned short* ap = hrd + aoff;
    f32x4 az0 = {0.f,0.f,0.f,0.f}, az1 = az0, ar0 = az0, ar1 = az0, ah0 = az0, ah1 = az0;
#pragma unroll
    for (int ks = 0; ks < 8; ++ks) {
      bfv8 a0 = *(const bfv8*)(ap + (ks << 6));
      bfv8 a1 = *(const bfv8*)(ap + (ks << 6) + 32);
      const unsigned short* wp = Wl + ((((kh << 6) + (ks << 3) + hi) * 16 + l15) * 8);
      bfv8 wz0 = *(const bfv8*)(wp);
      bfv8 wr0 = *(const bfv8*)(wp + (1 << 14));
      bfv8 wh0 = *(const bfv8*)(wp + (2 << 14));
      bfv8 wz1 = *(const bfv8*)(wp + 512);            // kb+4
      bfv8 wr1 = *(const bfv8*)(wp + (1 << 14) + 512);
      bfv8 wh1 = *(const bfv8*)(wp + (2 << 14) + 512);
      az0 = mfma16(a0, wz0, az0); ar0 = mfma16(a0, wr0, ar0); ah0 = mfma16(a0, wh0, ah0);
      az1 = mfma16(a1, wz1, az1); ar1 = mfma16(a1, wr1, ar1); ah1 = mfma16(a1, wh1, ah1);
    }
    f32x4 az = az0 + az1, ar = ar0 + ar1, ah = ah0 + ah1;

    // consume prefetched XP/tok (kh=0), then issue next step's prefetch
    float xz[4], xr[4], xh[4]; int tok[4];
    if (kh == 0) {
#pragma unroll
      for (int q = 0; q < 4; ++q) {
        xz[q] = bf2f(px[q * 3 + 0]);
        xr[q] = bf2f(px[q * 3 + 1]);
        xh[q] = bf2f(px[q * 3 + 2]);
      }
      tok[0] = ptok.x; tok[1] = ptok.y; tok[2] = ptok.z; tok[3] = ptok.w;
      if (s + 1 < T_SEQ) {
        const int tn = dir ? (T_SEQ - 2 - s) : (s + 1);
        const unsigned short* xs = xpb + (size_t)tn * XT_STRIDE;
#pragma unroll
        for (int q = 0; q < 4; ++q)
#pragma unroll
          for (int g = 0; g < 3; ++g)
            px[q * 3 + g] = xs[(rb + q) * 48 + g * 16 + l15];
        ptok = *(const int4*)(tokT + tn * BATCH + ob);
      }
    }

    // K-half handoff: kh=1 publishes partials into red[s&1] (13-pad rows)
    if (kh == 1) {
#pragma unroll
      for (int j = 0; j < 4; ++j) {
        red[s & 1][wlo][lane][j]     = az[j];
        red[s & 1][wlo][lane][4 + j] = ar[j];
        red[s & 1][wlo][lane][8 + j] = ah[j];
      }
    }
    WAIT_LGKM(); SCHED0(); SBAR(); SCHED0(); // the ONE per-step barrier

    if (kh == 0) {
#pragma unroll
      for (int j = 0; j < 4; ++j) {
        az[j] += red[s & 1][wlo][lane][j];
        ar[j] += red[s & 1][wlo][lane][4 + j];
        ah[j] += red[s & 1][wlo][lane][8 + j];
      }
#pragma unroll
      for (int q = 0; q < 4; ++q) {
        const float z  = 1.f / (1.f + __expf(-(xz[q] + az[q] + bz)));
        const float r  = 1.f / (1.f + __expf(-(xr[q] + ar[q] + brg)));
        const float hh = tanhf(xh[q] + r * (ah[q] + bhg));
        float hn = z * hreg[q] + (1.f - z) * hh;
        if (tok[q] == 0) hn = hreg[q]; // masked step carries state
        hreg[q] = hn;
        // direct coherent h store (owner lane, u16; 16 lanes/row coalesce)
        __hip_atomic_store(hwr + ((size_t)(ob + q) << 11) + woff, f2bf(hn),
                           __ATOMIC_RELAXED, __HIP_MEMORY_SCOPE_AGENT);
        out[((size_t)((ob + q) * T_SEQ + t) << 11) + woff] = hn;
      }
      if (s + 1 < T_SEQ) {
        WAIT_VM(); SCHED0(); // drain THIS wave's stores (release)
        if (lane == 0)
          __hip_atomic_fetch_add(myflag, 1u, __ATOMIC_RELAXED, __HIP_MEMORY_SCOPE_AGENT);
      }
    }
  }
}

extern "C" void kernel_launch(void* const* d_in, const int* in_sizes, int n_in,
                              void* d_out, int out_size, void* d_ws, size_t ws_size,
                              hipStream_t stream) {
  const int* tokens = (const int*)d_in[0];
  const float* emb  = (const float*)d_in[1];
  const float* Wx_f = (const float*)d_in[2];
  const float* Wh_f = (const float*)d_in[3];
  const float* b_f  = (const float*)d_in[4];
  const float* Wx_b = (const float*)d_in[5];
  const float* Wh_b = (const float*)d_in[6];
  const float* b_b  = (const float*)d_in[7];
  const float* fc_W = (const float*)d_in[8];
  const float* fc_b = (const float*)d_in[9];
  float* out = (float*)d_out;

  // workspace layout (~446 MB)
  char* w = (char*)d_ws;
  unsigned short* XPn = (unsigned short*)w; w += (size_t)NROWS * N6U * 2;   // 384 MiB
  unsigned short* Xbf = (unsigned short*)w; w += (size_t)NROWS * EMB_D * 2; // 32 MiB
  unsigned short* WxT = (unsigned short*)w; w += (size_t)N6U * EMB_D * 2;   // 6 MiB
  unsigned short* WhT = (unsigned short*)w; w += (size_t)N6U * UNITS * 2;   // 12 MiB
  unsigned short* fcWT = (unsigned short*)w; w += (size_t)UNITS * 2048 * 2; // 4 MiB
  unsigned short* hbR = (unsigned short*)w; w += (size_t)HROT * HSTR * 2;   // 8 MiB
  float* biasX = (float*)w; w += N6U * 4;
  float* biasH = (float*)w; w += N6U * 4;
  int* tokT = (int*)w; w += NROWS * 4;                                      // 128 KB
  unsigned int* bar = (unsigned int*)w; w += 2048 * sizeof(unsigned int);   // 8 KB padded

  // only buffer 15 is read before being written (step 0 reads h_{-1} = 0)
  (void)hipMemsetAsync((void*)(hbR + (size_t)(HROT - 1) * HSTR), 0, (size_t)HSTR * 2, stream);
  (void)hipMemsetAsync((void*)bar, 0, 2048 * sizeof(unsigned int), stream);

  // weight prep (f32 -> bf16, [N][K] layouts) + token transpose
  k_transpose<<<dim3(EMB_D / 32, N3U / 32), 256, 0, stream>>>(Wx_f, WxT, EMB_D, N3U);
  k_transpose<<<dim3(EMB_D / 32, N3U / 32), 256, 0, stream>>>(Wx_b, WxT + (size_t)N3U * EMB_D, EMB_D, N3U);
  k_transpose<<<dim3(UNITS / 32, N3U / 32), 256, 0, stream>>>(Wh_f, WhT, UNITS, N3U);
  k_transpose<<<dim3(UNITS / 32, N3U / 32), 256, 0, stream>>>(Wh_b, WhT + (size_t)N3U * UNITS, UNITS, N3U);
  k_transpose<<<dim3(2048 / 32, 1024 / 32), 256, 0, stream>>>(fc_W, fcWT, 2048, 1024);
  k_bias<<<24, 256, 0, stream>>>(b_f, b_b, biasX, biasH);
  k_tokt<<<NROWS / 256, 256, 0, stream>>>(tokens, tokT);
  k_gather<<<(NROWS * 128) / 256, 256, 0, stream>>>(tokens, emb, Xbf);

  // input projections, both dirs, scattered into scan-ordered XPn (mode 0)
  k_gemm<<<dim3(NROWS / 128, N6U / 128), 256, 0, stream>>>(Xbf, WxT, biasX, XPn, NROWS, N6U, EMB_D, 0);

  // fused persistent bidirectional scan (256 steps inside one kernel)
  k_scan<<<256, 512, 0, stream>>>(XPn, WhT, biasH, tokT, hbR, out, bar);

  // hidden = [h_f|h_b] @ fc_W + fc_b (final state: step 255 -> buffer 15)
  k_gemm<<<dim3(1, 8), 256, 0, stream>>>(hbR + (size_t)(HROT - 1) * HSTR, fcWT, fc_b,
                                         out + (size_t)NROWS * 2048, BATCH, UNITS, 2048, 1);
}

// Round 16
// 2330.178 us; speedup vs baseline: 1.4812x; 1.4812x over previous
//
#include <hip/hip_runtime.h>

// ---------------------------------------------------------------------------
// Bidirectional GRU encoder (Keras v2, reset_after=True, mask_zero)
// Round 16 = round 12 base + TWO-LEVEL BROADCAST BARRIER:
//   Round 15's regression (8x poll traffic -> +50% time) + round 5's add-
//   contention (-> 16us/step) identify fabric self-interference as the
//   dominant scan cost. Now: 64 WGs/group add to 8 padded sub-counters
//   (unchanged); ONLY the group aggregator WG (ut==0) polls them, then
//   publishes gen[grp]=s+1; all other WGs poll that single line (1 read/iter,
//   8x less poll traffic). Rotating h buffers / coherent stores / 1-in-16
//   fence / minimal-wait barriers unchanged (validated rounds 10-14).
// ---------------------------------------------------------------------------

#define T_SEQ 256
#define BATCH 128
#define EMB_D 512
#define UNITS 1024
#define NROWS (BATCH * T_SEQ) /* 32768 */
#define N3U 3072
#define N6U 6144
// XPn element strides: [t]=786432, [dir]=393216, [ut]=6144, [b]=48, [g]=16
#define XT_STRIDE 786432
#define HSTR (BATCH * 2048) /* elements per h buffer (512 KB) */
#define HROT 16

#define SBAR()      __builtin_amdgcn_s_barrier()
#define SCHED0()    __builtin_amdgcn_sched_barrier(0)
#define WAIT_LGKM() asm volatile("s_waitcnt lgkmcnt(0)" ::: "memory")
#define WAIT_VM()   asm volatile("s_waitcnt vmcnt(0)" ::: "memory")

typedef __attribute__((ext_vector_type(8))) __bf16 bfv8;
typedef __attribute__((ext_vector_type(4))) float f32x4;

__device__ inline unsigned short f2bf(float f) {
  union { float f; unsigned int u; } x; x.f = f;
  unsigned int u = x.u;
  unsigned int r = (u + 0x7fffu + ((u >> 16) & 1u)) >> 16; // RNE
  return (unsigned short)r;
}
__device__ inline float bf2f(unsigned short h) {
  union { unsigned int u; float f; } x; x.u = ((unsigned int)h) << 16;
  return x.f;
}
__device__ inline f32x4 mfma16(bfv8 a, bfv8 b, f32x4 c) {
  return __builtin_amdgcn_mfma_f32_16x16x32_bf16(a, b, c, 0, 0, 0);
}
__device__ inline void gl_lds16(const unsigned short* g, unsigned short* l) {
  __builtin_amdgcn_global_load_lds(
      (const __attribute__((address_space(1))) void*)g,
      (__attribute__((address_space(3))) void*)l, 16, 0, 0);
}

// dst[N][K] (bf16) = src[K][N] (f32), 32x32 LDS-tiled transpose
__global__ __launch_bounds__(256) void k_transpose(const float* __restrict__ src,
                                                   unsigned short* __restrict__ dst,
                                                   int K, int N) {
  __shared__ float tile[32][33];
  int k0 = blockIdx.x * 32, n0 = blockIdx.y * 32;
  int tx = threadIdx.x & 31, ty = threadIdx.x >> 5;
#pragma unroll
  for (int i = 0; i < 4; ++i)
    tile[ty + i * 8][tx] = src[(size_t)(k0 + ty + i * 8) * N + n0 + tx];
  __syncthreads();
#pragma unroll
  for (int i = 0; i < 4; ++i)
    dst[(size_t)(n0 + ty + i * 8) * K + k0 + tx] = f2bf(tile[tx][ty + i * 8]);
}

// Xbf[32768][512] bf16 = emb[tokens[row]]
__global__ __launch_bounds__(256) void k_gather(const int* __restrict__ tokens,
                                                const float* __restrict__ emb,
                                                unsigned short* __restrict__ Xbf) {
  int idx = blockIdx.x * 256 + threadIdx.x; // one float4 per thread
  int row = idx >> 7;
  int c4 = (idx & 127) * 4;
  int tok = tokens[row];
  float4 v = *(const float4*)(emb + (size_t)tok * EMB_D + c4);
  ushort4 p;
  p.x = f2bf(v.x); p.y = f2bf(v.y); p.z = f2bf(v.z); p.w = f2bf(v.w);
  *(ushort4*)(Xbf + (size_t)row * EMB_D + c4) = p;
}

// biasX[6144] = [b_f[0] | b_b[0]],  biasH[6144] = [b_f[1] | b_b[1]]
__global__ __launch_bounds__(256) void k_bias(const float* __restrict__ bf_,
                                              const float* __restrict__ bb_,
                                              float* __restrict__ biasX,
                                              float* __restrict__ biasH) {
  int i = blockIdx.x * 256 + threadIdx.x;
  if (i >= N6U) return;
  if (i < N3U) { biasX[i] = bf_[i];        biasH[i] = bf_[N3U + i]; }
  else         { biasX[i] = bb_[i - N3U];  biasH[i] = bb_[i]; }
}

// tokT[t][b] = tokens[b][t]
__global__ __launch_bounds__(256) void k_tokt(const int* __restrict__ tokens,
                                              int* __restrict__ tokT) {
  int i = blockIdx.x * 256 + threadIdx.x; // 32768
  int b = i >> 8, t = i & 255;
  tokT[t * BATCH + b] = tokens[i];
}

// C = A[M][K](bf16) @ BT[N][K](bf16)^T + bias[N]
// mode 0: scatter bf16 into XPn[t][dir][ut][b][g][16]; mode 1: f32 row-major.
__global__ __launch_bounds__(256) void k_gemm(const unsigned short* __restrict__ A,
                                              const unsigned short* __restrict__ BT,
                                              const float* __restrict__ bias,
                                              void* __restrict__ C,
                                              int M, int N, int K, int mode) {
  __shared__ unsigned short As[128 * 32];
  __shared__ unsigned short Bs[128 * 32];
  const int mt = blockIdx.x, nt = blockIdx.y;
  const int tid = threadIdx.x;
  const int wid = tid >> 6, lane = tid & 63;
  const int wm = (wid >> 1) * 64, wn = (wid & 1) * 64;
  const int l15 = lane & 15, lk = (lane >> 4) * 8;

  f32x4 acc[4][4];
#pragma unroll
  for (int i = 0; i < 4; ++i)
#pragma unroll
    for (int j = 0; j < 4; ++j) acc[i][j] = (f32x4){0.f, 0.f, 0.f, 0.f};

  const int r = tid >> 2;          // staging row 0..63
  const int cc = (tid & 3) * 8;    // staging col (elements)
  const unsigned short* ga0 = A + (size_t)(mt * 128 + r) * K + cc;
  const unsigned short* ga1 = ga0 + (size_t)64 * K;
  const unsigned short* gb0 = BT + (size_t)(nt * 128 + r) * K + cc;
  const unsigned short* gb1 = gb0 + (size_t)64 * K;
  unsigned short* lA0 = As + r * 32 + cc;        // byte off = tid*16, wave-linear
  unsigned short* lA1 = As + (64 + r) * 32 + cc;
  unsigned short* lB0 = Bs + r * 32 + cc;
  unsigned short* lB1 = Bs + (64 + r) * 32 + cc;

  for (int k0 = 0; k0 < K; k0 += 32) {
    __syncthreads(); // previous iter's LDS reads complete
    gl_lds16(ga0 + k0, lA0);
    gl_lds16(ga1 + k0, lA1);
    gl_lds16(gb0 + k0, lB0);
    gl_lds16(gb1 + k0, lB1);
    __syncthreads(); // loads landed
    bfv8 af[4], bfr[4];
#pragma unroll
    for (int i = 0; i < 4; ++i) {
      af[i]  = *(const bfv8*)(As + (wm + i * 16 + l15) * 32 + lk);
      bfr[i] = *(const bfv8*)(Bs + (wn + i * 16 + l15) * 32 + lk);
    }
#pragma unroll
    for (int i = 0; i < 4; ++i)
#pragma unroll
      for (int j = 0; j < 4; ++j) acc[i][j] = mfma16(af[i], bfr[j], acc[i][j]);
  }

#pragma unroll
  for (int j = 0; j < 4; ++j) {
    const int col = nt * 128 + wn + j * 16 + l15;
    const float bv = bias[col];
    const int dirc = (col >= N3U) ? 1 : 0;
    const int cm = col - dirc * N3U;
    const int g = cm >> 10;
    const int uu = cm & 1023;
    const size_t cbase = (size_t)dirc * 393216 + (size_t)(uu >> 4) * 6144 +
                         (size_t)g * 16 + (uu & 15);
#pragma unroll
    for (int i = 0; i < 4; ++i) {
      const int row0 = mt * 128 + wm + i * 16 + (lane >> 4) * 4;
#pragma unroll
      for (int q = 0; q < 4; ++q) {
        const float v = acc[i][j][q] + bv;
        const int row = row0 + q;
        if (mode == 1) {
          ((float*)C)[(size_t)row * N + col] = v;
        } else {
          const int b = row >> 8, tt = row & 255;
          ((unsigned short*)C)[(size_t)tt * XT_STRIDE + cbase + (size_t)b * 48] = f2bf(v);
        }
      }
    }
  }
}

// ---------------------------------------------------------------------------
// Persistent fused GRU scan. Grid = 256 WGs (1/CU, ~108KB LDS):
//   grp = bid&3 -> (dir,mg); ut = bid>>2 (group g on XCDs g and g+4).
// ALL gate weights in LDS: Wl[gate][kb][u][8] (96 KB, staged once).
// h mirror: 16 rotating buffers; coherent sc1 u64 stores; cached reads;
// acquire fence only at s%16==15; minimal-wait raw barriers.
// Barrier: adds to 8 padded sub-counters; aggregator WG (ut==0) polls them
// and publishes gen[grp]; everyone else polls gen[grp] only (1 read/iter).
// ---------------------------------------------------------------------------
__global__ __launch_bounds__(256) void k_scan(const unsigned short* __restrict__ XPn,
                                              const unsigned short* __restrict__ WhT,
                                              const float* __restrict__ biasH,
                                              const int* __restrict__ tokT,
                                              unsigned short* __restrict__ hbR,
                                              float* __restrict__ out,
                                              unsigned int* __restrict__ bar) {
  __shared__ unsigned short Wl[3 * 128 * 16 * 8]; // 96 KB  [g][kb][u][8]
  __shared__ unsigned short xb[64 * 48];          // 6 KB XP step tile
  __shared__ int tkb[64];
  __shared__ unsigned short bounce[64 * 24];      // 3 KB, padded rows

  const int bid = blockIdx.x;
  const int grp = bid & 3;   // one group per {XCD g, XCD g+4} pair
  const int dir = grp >> 1;
  const int mg  = grp & 1;
  const int ut  = bid >> 2;  // 0..63
  const int u0 = ut * 16, m0 = mg * 64;
  const int sub = ut & 7;    // 8 WGs per padded sub-counter
  const int tid = threadIdx.x;

  // stage all 3 gates' Wh slice -> LDS (once)
  for (int c = tid; c < 6144; c += 256) {
    const int g  = c >> 11;         // gate
    const int kb = (c >> 4) & 127;  // k-block of 8
    const int uu = c & 15;
    *(uint4*)(Wl + (((g << 7) | kb) * 16 + uu) * 8) =
        *(const uint4*)(WhT + (((size_t)(dir * N3U + (g << 10) + u0 + uu)) << 10) + (kb << 3));
  }

  const int lane = tid & 63, wid = tid >> 6;
  const int l15 = lane & 15, hi = lane >> 4;
  const size_t aoff = ((size_t)(m0 + wid * 16 + l15) << 11) + (dir << 10) + (hi << 3);
  const int u = u0 + l15;
  const float bz  = biasH[dir * N3U + u];
  const float brg = biasH[dir * N3U + 1024 + u];
  const float bhg = biasH[dir * N3U + 2048 + u];
  const int rb = wid * 16 + (hi << 2); // local row of this lane's 4 outputs
  const int ob = m0 + rb;
  const size_t woff = (dir << 10) + u;
  const int sr = tid >> 2, sc4 = (tid & 3) << 2;
  const size_t soff = ((size_t)(m0 + sr) << 11) + (dir << 10) + u0 + sc4;

  // barrier lines: sub-counters at ((grp<<3)|sub)<<6; gen at 2048+(grp<<6)
  unsigned int* genp = &bar[2048 + (grp << 6)];

  // contiguous per-step XP tile base for this WG
  const unsigned short* xpb = XPn + (size_t)dir * 393216 + (size_t)ut * 6144 + (size_t)m0 * 48;

  // prologue prefetch: step 0
  unsigned long long pf0, pf1, pf2; int pft = 0;
  {
    const int t0 = dir ? (T_SEQ - 1) : 0;
    const unsigned long long* xs = (const unsigned long long*)(xpb + (size_t)t0 * XT_STRIDE);
    pf0 = xs[tid]; pf1 = xs[tid + 256]; pf2 = xs[tid + 512];
    if (tid < 64) pft = tokT[t0 * BATCH + m0 + tid];
  }

  float hreg[4] = {0.f, 0.f, 0.f, 0.f};
  float oreg[4];
  __syncthreads(); // Wl staged (full drain ok, once)

  for (int s = 0; s < T_SEQ; ++s) {
    const int t = dir ? (T_SEQ - 1 - s) : s;
    const unsigned short* hrd = hbR + (size_t)((s + HROT - 1) & (HROT - 1)) * HSTR; // h_{s-1}
    unsigned short* hwr       = hbR + (size_t)(s & (HROT - 1)) * HSTR;              // h_s

    // issue h loads early (consumed via compiler-counted waits in MFMA loop)
    const unsigned short* ap = hrd + aoff;
    bfv8 hA[16], hB[16];
#pragma unroll
    for (int ks = 0; ks < 16; ++ks) {
      hA[ks] = *(const bfv8*)(ap + (ks << 6));
      hB[ks] = *(const bfv8*)(ap + (ks << 6) + 32);
    }

    // stage this step's prefetched XP+tok tile into LDS
    {
      unsigned long long* xd = (unsigned long long*)xb;
      xd[tid] = pf0; xd[tid + 256] = pf1; xd[tid + 512] = pf2;
      if (tid < 64) tkb[tid] = pft;
    }
    WAIT_LGKM(); SCHED0(); SBAR(); SCHED0(); // B1: xb ready; vmem in flight

    float xz[4], xr[4], xh[4]; int tok[4];
#pragma unroll
    for (int q = 0; q < 4; ++q) {
      const int xo = (rb + q) * 48 + l15;
      xz[q] = bf2f(xb[xo]);
      xr[q] = bf2f(xb[xo + 16]);
      xh[q] = bf2f(xb[xo + 32]);
      tok[q] = tkb[rb + q];
    }

    // prefetch next step's XP+tok (stays in flight; drained at B3)
    if (s + 1 < T_SEQ) {
      const int tn = dir ? (T_SEQ - 2 - s) : (s + 1);
      const unsigned long long* xs = (const unsigned long long*)(xpb + (size_t)tn * XT_STRIDE);
      pf0 = xs[tid]; pf1 = xs[tid + 256]; pf2 = xs[tid + 512];
      if (tid < 64) pft = tokT[tn * BATCH + m0 + tid];
    }

    f32x4 az0 = {0.f,0.f,0.f,0.f}, az1 = az0, ar0 = az0, ar1 = az0, ah0 = az0, ah1 = az0;
#pragma unroll
    for (int ks = 0; ks < 16; ++ks) { // fully unrolled; h streamed into VGPRs
      const unsigned short* wp = Wl + (((ks << 3) + hi) * 16 + l15) * 8;
      bfv8 wz0 = *(const bfv8*)(wp);
      bfv8 wr0 = *(const bfv8*)(wp + (1 << 14));
      bfv8 wh0 = *(const bfv8*)(wp + (2 << 14));
      bfv8 wz1 = *(const bfv8*)(wp + 512);            // kb+4
      bfv8 wr1 = *(const bfv8*)(wp + (1 << 14) + 512);
      bfv8 wh1 = *(const bfv8*)(wp + (2 << 14) + 512);
      az0 = mfma16(hA[ks], wz0, az0); ar0 = mfma16(hA[ks], wr0, ar0); ah0 = mfma16(hA[ks], wh0, ah0);
      az1 = mfma16(hB[ks], wz1, az1); ar1 = mfma16(hB[ks], wr1, ar1); ah1 = mfma16(hB[ks], wh1, ah1);
    }
    f32x4 az = az0 + az1, ar = ar0 + ar1, ah = ah0 + ah1;

#pragma unroll
    for (int q = 0; q < 4; ++q) {
      const float z  = 1.f / (1.f + __expf(-(xz[q] + az[q] + bz)));
      const float r  = 1.f / (1.f + __expf(-(xr[q] + ar[q] + brg)));
      const float hh = tanhf(xh[q] + r * (ah[q] + bhg));
      float hn = z * hreg[q] + (1.f - z) * hh;
      if (tok[q] == 0) hn = hreg[q]; // masked step carries state
      hreg[q] = hn;
      oreg[q] = hn;                           // out store deferred past drain
      bounce[(rb + q) * 24 + l15] = f2bf(hn); // padded re-layout tile
    }

    WAIT_LGKM(); SCHED0(); SBAR(); SCHED0(); // B2: bounce ready; XP in flight
    {
      unsigned long long v = *(const unsigned long long*)(bounce + sr * 24 + sc4);
      // write-through to coherent point: visible device-wide once vmcnt acks
      __hip_atomic_store((unsigned long long*)(hwr + soff), v,
                         __ATOMIC_RELAXED, __HIP_MEMORY_SCOPE_AGENT);
    }

    if (s + 1 < T_SEQ) {
      WAIT_VM(); SCHED0(); SBAR(); SCHED0(); // B3: h stores ACK'd (release)
      // out stores AFTER the release drain: ACK overlaps the poll below
#pragma unroll
      for (int q = 0; q < 4; ++q)
        out[((size_t)((ob + q) * T_SEQ + t) << 11) + woff] = oreg[q];
      if (tid == 0)
        __hip_atomic_fetch_add(&bar[((grp << 3) | sub) << 6], 1u,
                               __ATOMIC_RELAXED, __HIP_MEMORY_SCOPE_AGENT);
      if (ut == 0) {
        // aggregator: poll the 8 sub-counters (only 4 WGs device-wide do this)
        if (tid < 8) {
          const unsigned tgt = 8u * (unsigned)(s + 1);
          unsigned int* p = &bar[((grp << 3) | tid) << 6];
          while (__hip_atomic_load(p, __ATOMIC_RELAXED, __HIP_MEMORY_SCOPE_AGENT) < tgt)
            __builtin_amdgcn_s_sleep(2);
        }
        // all 8 lanes reconverged => all counters seen; publish generation
        if (tid == 0)
          __hip_atomic_store(genp, (unsigned)(s + 1),
                             __ATOMIC_RELAXED, __HIP_MEMORY_SCOPE_AGENT);
      } else {
        // everyone else: poll ONE broadcast line
        if (tid == 0) {
          const unsigned tgt = (unsigned)(s + 1);
          while (__hip_atomic_load(genp, __ATOMIC_RELAXED, __HIP_MEMORY_SCOPE_AGENT) < tgt)
            __builtin_amdgcn_s_sleep(2);
        }
      }
      // rotation-boundary acquire fence (per CU; wave 0 executes it)
      if (tid == 0 && ((s & (HROT - 1)) == HROT - 1))
        __builtin_amdgcn_fence(__ATOMIC_ACQUIRE, "agent");
      SBAR(); SCHED0();                      // B4: release the WG
    } else {
      // last step: store directly (kernel end drains/flushes)
#pragma unroll
      for (int q = 0; q < 4; ++q)
        out[((size_t)((ob + q) * T_SEQ + t) << 11) + woff] = oreg[q];
    }
  }
}

extern "C" void kernel_launch(void* const* d_in, const int* in_sizes, int n_in,
                              void* d_out, int out_size, void* d_ws, size_t ws_size,
                              hipStream_t stream) {
  const int* tokens = (const int*)d_in[0];
  const float* emb  = (const float*)d_in[1];
  const float* Wx_f = (const float*)d_in[2];
  const float* Wh_f = (const float*)d_in[3];
  const float* b_f  = (const float*)d_in[4];
  const float* Wx_b = (const float*)d_in[5];
  const float* Wh_b = (const float*)d_in[6];
  const float* b_b  = (const float*)d_in[7];
  const float* fc_W = (const float*)d_in[8];
  const float* fc_b = (const float*)d_in[9];
  float* out = (float*)d_out;

  // workspace layout (~446 MB)
  char* w = (char*)d_ws;
  unsigned short* XPn = (unsigned short*)w; w += (size_t)NROWS * N6U * 2;   // 384 MiB
  unsigned short* Xbf = (unsigned short*)w; w += (size_t)NROWS * EMB_D * 2; // 32 MiB
  unsigned short* WxT = (unsigned short*)w; w += (size_t)N6U * EMB_D * 2;   // 6 MiB
  unsigned short* WhT = (unsigned short*)w; w += (size_t)N6U * UNITS * 2;   // 12 MiB
  unsigned short* fcWT = (unsigned short*)w; w += (size_t)UNITS * 2048 * 2; // 4 MiB
  unsigned short* hbR = (unsigned short*)w; w += (size_t)HROT * HSTR * 2;   // 8 MiB
  float* biasX = (float*)w; w += N6U * 4;
  float* biasH = (float*)w; w += N6U * 4;
  int* tokT = (int*)w; w += NROWS * 4;                                      // 128 KB
  unsigned int* bar = (unsigned int*)w; w += 4096 * sizeof(unsigned int);   // 16 KB padded

  // only buffer 15 is read before being written (step 0 reads h_{-1} = 0)
  (void)hipMemsetAsync((void*)(hbR + (size_t)(HROT - 1) * HSTR), 0, (size_t)HSTR * 2, stream);
  (void)hipMemsetAsync((void*)bar, 0, 4096 * sizeof(unsigned int), stream);

  // weight prep (f32 -> bf16, [N][K] layouts) + token transpose
  k_transpose<<<dim3(EMB_D / 32, N3U / 32), 256, 0, stream>>>(Wx_f, WxT, EMB_D, N3U);
  k_transpose<<<dim3(EMB_D / 32, N3U / 32), 256, 0, stream>>>(Wx_b, WxT + (size_t)N3U * EMB_D, EMB_D, N3U);
  k_transpose<<<dim3(UNITS / 32, N3U / 32), 256, 0, stream>>>(Wh_f, WhT, UNITS, N3U);
  k_transpose<<<dim3(UNITS / 32, N3U / 32), 256, 0, stream>>>(Wh_b, WhT + (size_t)N3U * UNITS, UNITS, N3U);
  k_transpose<<<dim3(2048 / 32, 1024 / 32), 256, 0, stream>>>(fc_W, fcWT, 2048, 1024);
  k_bias<<<24, 256, 0, stream>>>(b_f, b_b, biasX, biasH);
  k_tokt<<<NROWS / 256, 256, 0, stream>>>(tokens, tokT);
  k_gather<<<(NROWS * 128) / 256, 256, 0, stream>>>(tokens, emb, Xbf);

  // input projections, both dirs, scattered into scan-ordered XPn (mode 0)
  k_gemm<<<dim3(NROWS / 128, N6U / 128), 256, 0, stream>>>(Xbf, WxT, biasX, XPn, NROWS, N6U, EMB_D, 0);

  // fused persistent bidirectional scan (256 steps inside one kernel)
  k_scan<<<256, 256, 0, stream>>>(XPn, WhT, biasH, tokT, hbR, out, bar);

  // hidden = [h_f|h_b] @ fc_W + fc_b (final state: step 255 -> buffer 15)
  k_gemm<<<dim3(1, 8), 256, 0, stream>>>(hbR + (size_t)(HROT - 1) * HSTR, fcWT, fc_b,
                                         out + (size_t)NROWS * 2048, BATCH, UNITS, 2048, 1);
}